// Round 6
// baseline (244.753 us; speedup 1.0000x reference)
//
#include <hip/hip_runtime.h>
#include <hip/hip_bf16.h>

#define DNBR   16
#define INDIM  128
#define OUTDIM 64

typedef __attribute__((ext_vector_type(8))) short bf16x8;
typedef __attribute__((ext_vector_type(4))) float f32x4;
typedef __attribute__((ext_vector_type(4))) unsigned u32x4;

union BF8 { bf16x8 v; u32x4 u; };

__device__ __forceinline__ unsigned cvt_pk_bf16(float lo, float hi) {
    unsigned r;
    asm("v_cvt_pk_bf16_f32 %0, %1, %2" : "=v"(r) : "v"(lo), "v"(hi));
    return r;
}

// static 4-way select (no runtime register indexing -> no scratch)
__device__ __forceinline__ int sel4i(const int* a, int g) {
    const int r = (g & 1) ? a[1] : a[0];
    const int s = (g & 1) ? a[3] : a[2];
    return (g & 2) ? s : r;
}
__device__ __forceinline__ float sel4f(const float* a, int g) {
    const float r = (g & 1) ? a[1] : a[0];
    const float s = (g & 1) ? a[3] : a[2];
    return (g & 2) ? s : r;
}

// ---------------- Phase 0: pre-pack W_fc into MFMA B-fragment order (bf16) ----
__global__ __launch_bounds__(256) void wprep(
    const float* __restrict__ W_fc, unsigned* __restrict__ wfrag)
{
    const int t = threadIdx.x;
    #pragma unroll
    for (int s4 = 0; s4 < 4; ++s4) {
        const int slot = t + 256 * s4;        // 0..1023
        const int lane = slot & 63;
        const int ckk  = slot >> 6;           // ct*4+kk
        const int ct = ckk >> 2, kk = ckk & 3;
        const int lm = lane & 15, lg = lane >> 4;
        const float* wr = W_fc + (size_t)(ct * 16 + lm) * INDIM + kk * 32 + lg * 8;
        const float4 w0 = *reinterpret_cast<const float4*>(wr);
        const float4 w1 = *reinterpret_cast<const float4*>(wr + 4);
        u32x4 o;
        o[0] = cvt_pk_bf16(w0.x, w0.y);
        o[1] = cvt_pk_bf16(w0.z, w0.w);
        o[2] = cvt_pk_bf16(w1.x, w1.y);
        o[3] = cvt_pk_bf16(w1.z, w1.w);
        *reinterpret_cast<u32x4*>(wfrag + (size_t)slot * 4) = o;
    }
}

// ---------------- Phase 1: z = h @ W_fc^T via bf16 MFMA, + s_src/s_dst -------
__global__ __launch_bounds__(256) void fc_mfma(
    const float* __restrict__ h, const unsigned* __restrict__ wfrag,
    const float* __restrict__ W_attn, __hip_bfloat16* __restrict__ zb,
    float* __restrict__ s_src, float* __restrict__ s_dst, int n)
{
    const int lane  = threadIdx.x & 63;
    const int wid   = threadIdx.x >> 6;
    const int node0 = blockIdx.x * 64 + wid * 16;
    if (node0 >= n) return;
    const int lm = lane & 15;
    const int lg = lane >> 4;

    bf16x8 bfrag[4][4];
    #pragma unroll
    for (int ct = 0; ct < 4; ++ct)
        #pragma unroll
        for (int kk = 0; kk < 4; ++kk) {
            BF8 u;
            u.u = *reinterpret_cast<const u32x4*>(wfrag + (size_t)((ct * 4 + kk) * 64 + lane) * 4);
            bfrag[ct][kk] = u.v;
        }

    const int arow = (node0 + lm < n) ? (node0 + lm) : (n - 1);
    const float* hr = h + (size_t)arow * INDIM;
    bf16x8 af[4];
    #pragma unroll
    for (int kk = 0; kk < 4; ++kk) {
        const float4 a0 = *reinterpret_cast<const float4*>(hr + kk * 32 + lg * 8);
        const float4 a1 = *reinterpret_cast<const float4*>(hr + kk * 32 + lg * 8 + 4);
        BF8 u;
        u.u[0] = cvt_pk_bf16(a0.x, a0.y);
        u.u[1] = cvt_pk_bf16(a0.z, a0.w);
        u.u[2] = cvt_pk_bf16(a1.x, a1.y);
        u.u[3] = cvt_pk_bf16(a1.z, a1.w);
        af[kk] = u.v;
    }

    f32x4 acc[4];
    #pragma unroll
    for (int ct = 0; ct < 4; ++ct) acc[ct] = (f32x4){0.f, 0.f, 0.f, 0.f};
    #pragma unroll
    for (int kk = 0; kk < 4; ++kk)
        #pragma unroll
        for (int ct = 0; ct < 4; ++ct)
            acc[ct] = __builtin_amdgcn_mfma_f32_16x16x32_bf16(af[kk], bfrag[ct][kk], acc[ct], 0, 0, 0);

    float ps[4] = {0.f, 0.f, 0.f, 0.f};
    float pd[4] = {0.f, 0.f, 0.f, 0.f};
    unsigned short* zbs = reinterpret_cast<unsigned short*>(zb);
    #pragma unroll
    for (int ct = 0; ct < 4; ++ct) {
        const float as = W_attn[ct * 16 + lm];
        const float ad = W_attn[OUTDIM + ct * 16 + lm];
        #pragma unroll
        for (int r = 0; r < 4; ++r) {
            const float v = acc[ct][r];                 // C[(lg*4+r)][ct*16+lm]
            const int grow = node0 + lg * 4 + r;
            if (grow < n)
                zbs[(size_t)grow * OUTDIM + ct * 16 + lm] =
                    (unsigned short)(cvt_pk_bf16(v, v) & 0xFFFFu);
            ps[r] = fmaf(v, as, ps[r]);
            pd[r] = fmaf(v, ad, pd[r]);
        }
    }
    #pragma unroll
    for (int off = 1; off < 16; off <<= 1) {
        #pragma unroll
        for (int r = 0; r < 4; ++r) {
            ps[r] += __shfl_xor(ps[r], off, 64);
            pd[r] += __shfl_xor(pd[r], off, 64);
        }
    }
    if (lm == 0) {
        #pragma unroll
        for (int r = 0; r < 4; ++r) {
            const int grow = node0 + lg * 4 + r;
            if (grow < n) { s_src[grow] = ps[r]; s_dst[grow] = pd[r]; }
        }
    }
}

// ---------------- exact entmax15 over 16 values (weights = y^2) ---------------
__device__ __forceinline__ void entmax15_weights(float x[DNBR], float wout[DNBR]) {
    float mx = x[0];
    #pragma unroll
    for (int j = 1; j < DNBR; ++j) mx = fmaxf(mx, x[j]);
    #pragma unroll
    for (int j = 0; j < DNBR; ++j) x[j] -= mx;

    float xs[DNBR];
    #pragma unroll
    for (int j = 0; j < DNBR; ++j) xs[j] = x[j];
    #pragma unroll
    for (int k = 2; k <= DNBR; k <<= 1) {
        #pragma unroll
        for (int s = k >> 1; s >= 1; s >>= 1) {
            #pragma unroll
            for (int i = 0; i < DNBR; ++i) {
                int l = i ^ s;
                if (l > i) {
                    const bool up = ((i & k) == 0);
                    float a = xs[i], b = xs[l];
                    float hi = fmaxf(a, b), lo = fminf(a, b);
                    xs[i] = up ? hi : lo;
                    xs[l] = up ? lo : hi;
                }
            }
        }
    }

    float taus[DNBR];
    float cs = 0.f, css = 0.f;
    int supp = 0;
    #pragma unroll
    for (int k = 0; k < DNBR; ++k) {
        cs  += xs[k];
        css += xs[k] * xs[k];
        const float kk = (float)(k + 1);
        const float mean   = cs  / kk;
        const float meansq = css / kk;
        const float ssv    = kk * (meansq - mean * mean);
        const float delta  = (1.f - ssv) / kk;
        const float sq     = (delta > 0.f) ? sqrtf(delta) : 0.f;
        taus[k] = mean - sq;
        supp += (taus[k] <= xs[k]) ? 1 : 0;
    }
    float tau_star = taus[0];
    #pragma unroll
    for (int k = 1; k < DNBR; ++k)
        tau_star = (supp - 1 == k) ? taus[k] : tau_star;

    #pragma unroll
    for (int j = 0; j < DNBR; ++j) {
        const float y = fmaxf(x[j] - tau_star, 0.f);
        wout[j] = y * y;
    }
}

// ---------------- Phase 2: one thread per node -> alpha[n][16] ----------------
__global__ __launch_bounds__(256) void alpha_kernel(
    const int* __restrict__ nbr, const float* __restrict__ wbias,
    const float* __restrict__ s_src, const float* __restrict__ s_dst,
    float* __restrict__ alpha, int n)
{
    const int node = blockIdx.x * 256 + threadIdx.x;
    if (node >= n) return;

    const int4*   nrow = reinterpret_cast<const int4*>(nbr + (size_t)node * DNBR);
    const float4* wrow = reinterpret_cast<const float4*>(wbias + (size_t)node * DNBR);
    const float sd = s_dst[node];

    float x[DNBR];
    #pragma unroll
    for (int q = 0; q < 4; ++q) {
        const int4 v   = nrow[q];
        const float4 t = wrow[q];
        const int   nb4[4] = {v.x, v.y, v.z, v.w};
        const float w4[4]  = {t.x, t.y, t.z, t.w};
        #pragma unroll
        for (int j = 0; j < 4; ++j) {
            float e = s_src[nb4[j]] + sd;
            e = (e >= 0.f) ? e : 0.01f * e;
            x[q * 4 + j] = 0.5f * (e + w4[j]);
        }
    }

    float wts[DNBR];
    entmax15_weights(x, wts);

    float4* arow = reinterpret_cast<float4*>(alpha + (size_t)node * DNBR);
    #pragma unroll
    for (int q = 0; q < 4; ++q)
        arow[q] = make_float4(wts[q * 4 + 0], wts[q * 4 + 1], wts[q * 4 + 2], wts[q * 4 + 3]);
}

// ---------------- Phase 3: wave per 2 nodes; 8B-per-lane gathers --------------
// lane = (g = lane>>4: neighbor subgroup j=4t+g, c4 = lane&15: channel quad).
// Per node: 4 gather instructions (each covers 4 z-rows, full 128B lines),
// then reduce over g via shfl_xor(16,32); lanes g==0 store coalesced float4.
__global__ __launch_bounds__(256) void out_kernel(
    const int* __restrict__ nbr, const float* __restrict__ alpha,
    const __hip_bfloat16* __restrict__ zb, float* __restrict__ out, int n)
{
    const int lane = threadIdx.x & 63;
    const int wv   = blockIdx.x * 4 + (threadIdx.x >> 6);
    const int n0   = wv * 2;
    if (n0 >= n) return;
    const int n1 = (n0 + 1 < n) ? (n0 + 1) : n0;
    const int g  = lane >> 4;
    const int c4 = lane & 15;

    int   nb0[DNBR], nb1[DNBR];
    float aw0[DNBR], aw1[DNBR];
    {
        const int4*   r0 = reinterpret_cast<const int4*>(nbr + (size_t)n0 * DNBR);
        const int4*   r1 = reinterpret_cast<const int4*>(nbr + (size_t)n1 * DNBR);
        const float4* a0 = reinterpret_cast<const float4*>(alpha + (size_t)n0 * DNBR);
        const float4* a1 = reinterpret_cast<const float4*>(alpha + (size_t)n1 * DNBR);
        #pragma unroll
        for (int q = 0; q < 4; ++q) {
            const int4 va = r0[q], vb = r1[q];
            nb0[4*q+0]=va.x; nb0[4*q+1]=va.y; nb0[4*q+2]=va.z; nb0[4*q+3]=va.w;
            nb1[4*q+0]=vb.x; nb1[4*q+1]=vb.y; nb1[4*q+2]=vb.z; nb1[4*q+3]=vb.w;
            const float4 ta = a0[q], tb = a1[q];
            aw0[4*q+0]=ta.x; aw0[4*q+1]=ta.y; aw0[4*q+2]=ta.z; aw0[4*q+3]=ta.w;
            aw1[4*q+0]=tb.x; aw1[4*q+1]=tb.y; aw1[4*q+2]=tb.z; aw1[4*q+3]=tb.w;
        }
    }

    const unsigned short* zs = reinterpret_cast<const unsigned short*>(zb);
    uint2 zv0[4], zv1[4];
    float av0[4], av1[4];
    #pragma unroll
    for (int t = 0; t < 4; ++t) {
        const int j0 = sel4i(&nb0[4*t], g);
        const int j1 = sel4i(&nb1[4*t], g);
        av0[t] = sel4f(&aw0[4*t], g);
        av1[t] = sel4f(&aw1[4*t], g);
        zv0[t] = *reinterpret_cast<const uint2*>(zs + (size_t)j0 * OUTDIM + c4 * 4);
        zv1[t] = *reinterpret_cast<const uint2*>(zs + (size_t)j1 * OUTDIM + c4 * 4);
    }

    float ac0[4] = {0.f, 0.f, 0.f, 0.f};
    float ac1[4] = {0.f, 0.f, 0.f, 0.f};
    #pragma unroll
    for (int t = 0; t < 4; ++t) {
        union { unsigned u; float f; } w;
        float f0, f1, f2, f3;
        w.u = zv0[t].x << 16;        f0 = w.f;
        w.u = zv0[t].x & 0xFFFF0000u; f1 = w.f;
        w.u = zv0[t].y << 16;        f2 = w.f;
        w.u = zv0[t].y & 0xFFFF0000u; f3 = w.f;
        ac0[0] = fmaf(av0[t], f0, ac0[0]);
        ac0[1] = fmaf(av0[t], f1, ac0[1]);
        ac0[2] = fmaf(av0[t], f2, ac0[2]);
        ac0[3] = fmaf(av0[t], f3, ac0[3]);
        w.u = zv1[t].x << 16;        f0 = w.f;
        w.u = zv1[t].x & 0xFFFF0000u; f1 = w.f;
        w.u = zv1[t].y << 16;        f2 = w.f;
        w.u = zv1[t].y & 0xFFFF0000u; f3 = w.f;
        ac1[0] = fmaf(av1[t], f0, ac1[0]);
        ac1[1] = fmaf(av1[t], f1, ac1[1]);
        ac1[2] = fmaf(av1[t], f2, ac1[2]);
        ac1[3] = fmaf(av1[t], f3, ac1[3]);
    }

    // reduce over g (lane bits 4,5)
    #pragma unroll
    for (int c = 0; c < 4; ++c) {
        ac0[c] += __shfl_xor(ac0[c], 16, 64);
        ac0[c] += __shfl_xor(ac0[c], 32, 64);
        ac1[c] += __shfl_xor(ac1[c], 16, 64);
        ac1[c] += __shfl_xor(ac1[c], 32, 64);
    }

    if (g == 0) {
        *reinterpret_cast<float4*>(out + (size_t)n0 * OUTDIM + c4 * 4) =
            make_float4(ac0[0], ac0[1], ac0[2], ac0[3]);
        if (n1 != n0)
            *reinterpret_cast<float4*>(out + (size_t)n1 * OUTDIM + c4 * 4) =
                make_float4(ac1[0], ac1[1], ac1[2], ac1[3]);
    }
}

extern "C" void kernel_launch(void* const* d_in, const int* in_sizes, int n_in,
                              void* d_out, int out_size, void* d_ws, size_t ws_size,
                              hipStream_t stream) {
    const float* h      = (const float*)d_in[0];
    const int*   nbr    = (const int*)  d_in[1];
    const float* wbias  = (const float*)d_in[2];
    const float* W_fc   = (const float*)d_in[3];
    const float* W_attn = (const float*)d_in[4];
    float* out = (float*)d_out;

    const int n = in_sizes[0] / INDIM;   // 100000

    // ws: zb (n*64 bf16) | s_src (n f32) | s_dst (n f32) | alpha (n*16 f32) | wfrag (4096 u32)
    __hip_bfloat16* zb = (__hip_bfloat16*)d_ws;
    float* s_src = (float*)((char*)d_ws + (size_t)n * OUTDIM * sizeof(__hip_bfloat16));
    float* s_dst = s_src + n;
    float* alpha = s_dst + n;
    unsigned* wfrag = (unsigned*)(alpha + (size_t)n * DNBR);

    wprep<<<1, 256, 0, stream>>>(W_fc, wfrag);
    fc_mfma<<<(n + 63) / 64, 256, 0, stream>>>(h, wfrag, W_attn, zb, s_src, s_dst, n);
    alpha_kernel<<<(n + 255) / 256, 256, 0, stream>>>(nbr, wbias, s_src, s_dst, alpha, n);
    out_kernel<<<(n + 7) / 8, 256, 0, stream>>>(nbr, alpha, zb, out, n);
}

// Round 7
// 67.118 us; speedup vs baseline: 3.6466x; 3.6466x over previous
//
#include <hip/hip_runtime.h>
#include <hip/hip_bf16.h>

#define DNBR   16
#define INDIM  128
#define OUTDIM 64

typedef __attribute__((ext_vector_type(8))) short bf16x8;
typedef __attribute__((ext_vector_type(4))) float f32x4;
typedef __attribute__((ext_vector_type(4))) unsigned u32x4;

union BF8 { bf16x8 v; u32x4 u; };

__device__ __forceinline__ unsigned cvt_pk_bf16(float lo, float hi) {
    unsigned r;
    asm("v_cvt_pk_bf16_f32 %0, %1, %2" : "=v"(r) : "v"(lo), "v"(hi));
    return r;
}

// ---------------- Phase 0: pre-pack W_fc into MFMA B-fragment order (bf16) ----
__global__ __launch_bounds__(256) void wprep(
    const float* __restrict__ W_fc, unsigned* __restrict__ wfrag)
{
    const int t = threadIdx.x;
    #pragma unroll
    for (int s4 = 0; s4 < 4; ++s4) {
        const int slot = t + 256 * s4;        // 0..1023
        const int lane = slot & 63;
        const int ckk  = slot >> 6;           // ct*4+kk
        const int ct = ckk >> 2, kk = ckk & 3;
        const int lm = lane & 15, lg = lane >> 4;
        const float* wr = W_fc + (size_t)(ct * 16 + lm) * INDIM + kk * 32 + lg * 8;
        const float4 w0 = *reinterpret_cast<const float4*>(wr);
        const float4 w1 = *reinterpret_cast<const float4*>(wr + 4);
        u32x4 o;
        o[0] = cvt_pk_bf16(w0.x, w0.y);
        o[1] = cvt_pk_bf16(w0.z, w0.w);
        o[2] = cvt_pk_bf16(w1.x, w1.y);
        o[3] = cvt_pk_bf16(w1.z, w1.w);
        *reinterpret_cast<u32x4*>(wfrag + (size_t)slot * 4) = o;
    }
}

// ---------------- Phase 1: z = h @ W_fc^T via bf16 MFMA, + s_src/s_dst -------
__global__ __launch_bounds__(256) void fc_mfma(
    const float* __restrict__ h, const unsigned* __restrict__ wfrag,
    const float* __restrict__ W_attn, __hip_bfloat16* __restrict__ zb,
    float* __restrict__ s_src, float* __restrict__ s_dst, int n)
{
    const int lane  = threadIdx.x & 63;
    const int wid   = threadIdx.x >> 6;
    const int node0 = blockIdx.x * 64 + wid * 16;
    if (node0 >= n) return;
    const int lm = lane & 15;
    const int lg = lane >> 4;

    bf16x8 bfrag[4][4];
    #pragma unroll
    for (int ct = 0; ct < 4; ++ct)
        #pragma unroll
        for (int kk = 0; kk < 4; ++kk) {
            BF8 u;
            u.u = *reinterpret_cast<const u32x4*>(wfrag + (size_t)((ct * 4 + kk) * 64 + lane) * 4);
            bfrag[ct][kk] = u.v;
        }

    const int arow = (node0 + lm < n) ? (node0 + lm) : (n - 1);
    const float* hr = h + (size_t)arow * INDIM;
    bf16x8 af[4];
    #pragma unroll
    for (int kk = 0; kk < 4; ++kk) {
        const float4 a0 = *reinterpret_cast<const float4*>(hr + kk * 32 + lg * 8);
        const float4 a1 = *reinterpret_cast<const float4*>(hr + kk * 32 + lg * 8 + 4);
        BF8 u;
        u.u[0] = cvt_pk_bf16(a0.x, a0.y);
        u.u[1] = cvt_pk_bf16(a0.z, a0.w);
        u.u[2] = cvt_pk_bf16(a1.x, a1.y);
        u.u[3] = cvt_pk_bf16(a1.z, a1.w);
        af[kk] = u.v;
    }

    f32x4 acc[4];
    #pragma unroll
    for (int ct = 0; ct < 4; ++ct) acc[ct] = (f32x4){0.f, 0.f, 0.f, 0.f};
    #pragma unroll
    for (int kk = 0; kk < 4; ++kk)
        #pragma unroll
        for (int ct = 0; ct < 4; ++ct)
            acc[ct] = __builtin_amdgcn_mfma_f32_16x16x32_bf16(af[kk], bfrag[ct][kk], acc[ct], 0, 0, 0);

    float ps[4] = {0.f, 0.f, 0.f, 0.f};
    float pd[4] = {0.f, 0.f, 0.f, 0.f};
    unsigned short* zbs = reinterpret_cast<unsigned short*>(zb);
    #pragma unroll
    for (int ct = 0; ct < 4; ++ct) {
        const float as = W_attn[ct * 16 + lm];
        const float ad = W_attn[OUTDIM + ct * 16 + lm];
        #pragma unroll
        for (int r = 0; r < 4; ++r) {
            const float v = acc[ct][r];                 // C[(lg*4+r)][ct*16+lm]
            const int grow = node0 + lg * 4 + r;
            if (grow < n)
                zbs[(size_t)grow * OUTDIM + ct * 16 + lm] =
                    (unsigned short)(cvt_pk_bf16(v, v) & 0xFFFFu);
            ps[r] = fmaf(v, as, ps[r]);
            pd[r] = fmaf(v, ad, pd[r]);
        }
    }
    #pragma unroll
    for (int off = 1; off < 16; off <<= 1) {
        #pragma unroll
        for (int r = 0; r < 4; ++r) {
            ps[r] += __shfl_xor(ps[r], off, 64);
            pd[r] += __shfl_xor(pd[r], off, 64);
        }
    }
    if (lm == 0) {
        #pragma unroll
        for (int r = 0; r < 4; ++r) {
            const int grow = node0 + lg * 4 + r;
            if (grow < n) { s_src[grow] = ps[r]; s_dst[grow] = pd[r]; }
        }
    }
}

// ---------------- exact entmax15 over 16 values (weights = y^2) ---------------
__device__ __forceinline__ void entmax15_weights(float x[DNBR], float wout[DNBR]) {
    float mx = x[0];
    #pragma unroll
    for (int j = 1; j < DNBR; ++j) mx = fmaxf(mx, x[j]);
    #pragma unroll
    for (int j = 0; j < DNBR; ++j) x[j] -= mx;

    float xs[DNBR];
    #pragma unroll
    for (int j = 0; j < DNBR; ++j) xs[j] = x[j];
    #pragma unroll
    for (int k = 2; k <= DNBR; k <<= 1) {
        #pragma unroll
        for (int s = k >> 1; s >= 1; s >>= 1) {
            #pragma unroll
            for (int i = 0; i < DNBR; ++i) {
                int l = i ^ s;
                if (l > i) {
                    const bool up = ((i & k) == 0);
                    float a = xs[i], b = xs[l];
                    float hi = fmaxf(a, b), lo = fminf(a, b);
                    xs[i] = up ? hi : lo;
                    xs[l] = up ? lo : hi;
                }
            }
        }
    }

    float taus[DNBR];
    float cs = 0.f, css = 0.f;
    int supp = 0;
    #pragma unroll
    for (int k = 0; k < DNBR; ++k) {
        cs  += xs[k];
        css += xs[k] * xs[k];
        const float kk = (float)(k + 1);
        const float mean   = cs  / kk;
        const float meansq = css / kk;
        const float ssv    = kk * (meansq - mean * mean);
        const float delta  = (1.f - ssv) / kk;
        const float sq     = (delta > 0.f) ? sqrtf(delta) : 0.f;
        taus[k] = mean - sq;
        supp += (taus[k] <= xs[k]) ? 1 : 0;
    }
    float tau_star = taus[0];
    #pragma unroll
    for (int k = 1; k < DNBR; ++k)
        tau_star = (supp - 1 == k) ? taus[k] : tau_star;

    #pragma unroll
    for (int j = 0; j < DNBR; ++j) {
        const float y = fmaxf(x[j] - tau_star, 0.f);
        wout[j] = y * y;
    }
}

// ---------------- Phase 2: one thread per node -> alpha[n][16] ----------------
__global__ __launch_bounds__(256) void alpha_kernel(
    const int* __restrict__ nbr, const float* __restrict__ wbias,
    const float* __restrict__ s_src, const float* __restrict__ s_dst,
    float* __restrict__ alpha, int n)
{
    const int node = blockIdx.x * 256 + threadIdx.x;
    if (node >= n) return;

    const int4*   nrow = reinterpret_cast<const int4*>(nbr + (size_t)node * DNBR);
    const float4* wrow = reinterpret_cast<const float4*>(wbias + (size_t)node * DNBR);
    const float sd = s_dst[node];

    float x[DNBR];
    #pragma unroll
    for (int q = 0; q < 4; ++q) {
        const int4 v   = nrow[q];
        const float4 t = wrow[q];
        const int   nb4[4] = {v.x, v.y, v.z, v.w};
        const float w4[4]  = {t.x, t.y, t.z, t.w};
        #pragma unroll
        for (int j = 0; j < 4; ++j) {
            float e = s_src[nb4[j]] + sd;
            e = (e >= 0.f) ? e : 0.01f * e;
            x[q * 4 + j] = 0.5f * (e + w4[j]);
        }
    }

    float wts[DNBR];
    entmax15_weights(x, wts);

    float4* arow = reinterpret_cast<float4*>(alpha + (size_t)node * DNBR);
    #pragma unroll
    for (int q = 0; q < 4; ++q)
        arow[q] = make_float4(wts[q * 4 + 0], wts[q * 4 + 1], wts[q * 4 + 2], wts[q * 4 + 3]);
}

// ---------------- Phase 3: wave per 2 nodes; 8B-per-lane gathers --------------
// lane = (g = lane>>4: neighbor slot j = 4t+g, c4 = lane&15: channel quad).
// Per-lane nbr/alpha loads straight from global (no local arrays -> no scratch).
// Per node: 4 z-gather instructions, each covering 4 full 128B z-rows.
// Reduce over g via shfl_xor(16,32); lanes g==0 store coalesced float4.
__global__ __launch_bounds__(256) void out_kernel(
    const int* __restrict__ nbr, const float* __restrict__ alpha,
    const __hip_bfloat16* __restrict__ zb, float* __restrict__ out, int n)
{
    const int lane = threadIdx.x & 63;
    const int wv   = blockIdx.x * 4 + (threadIdx.x >> 6);
    const int n0   = wv * 2;
    if (n0 >= n) return;
    const int n1 = (n0 + 1 < n) ? (n0 + 1) : n0;
    const int g  = lane >> 4;
    const int c4 = lane & 15;

    const unsigned short* zs = reinterpret_cast<const unsigned short*>(zb);
    const int* nr0 = nbr + (size_t)n0 * DNBR + g;
    const int* nr1 = nbr + (size_t)n1 * DNBR + g;
    const float* al0 = alpha + (size_t)n0 * DNBR + g;
    const float* al1 = alpha + (size_t)n1 * DNBR + g;

    // per-lane neighbor indices + alphas (named scalars, fully in registers)
    const int j00 = nr0[0],  j01 = nr0[4],  j02 = nr0[8],  j03 = nr0[12];
    const int j10 = nr1[0],  j11 = nr1[4],  j12 = nr1[8],  j13 = nr1[12];
    const float a00 = al0[0], a01 = al0[4], a02 = al0[8],  a03 = al0[12];
    const float a10 = al1[0], a11 = al1[4], a12 = al1[8],  a13 = al1[12];

    // all 8 z-gathers issued back-to-back
    const uint2 z00 = *reinterpret_cast<const uint2*>(zs + (size_t)j00 * OUTDIM + c4 * 4);
    const uint2 z01 = *reinterpret_cast<const uint2*>(zs + (size_t)j01 * OUTDIM + c4 * 4);
    const uint2 z02 = *reinterpret_cast<const uint2*>(zs + (size_t)j02 * OUTDIM + c4 * 4);
    const uint2 z03 = *reinterpret_cast<const uint2*>(zs + (size_t)j03 * OUTDIM + c4 * 4);
    const uint2 z10 = *reinterpret_cast<const uint2*>(zs + (size_t)j10 * OUTDIM + c4 * 4);
    const uint2 z11 = *reinterpret_cast<const uint2*>(zs + (size_t)j11 * OUTDIM + c4 * 4);
    const uint2 z12 = *reinterpret_cast<const uint2*>(zs + (size_t)j12 * OUTDIM + c4 * 4);
    const uint2 z13 = *reinterpret_cast<const uint2*>(zs + (size_t)j13 * OUTDIM + c4 * 4);

    float ac0[4] = {0.f, 0.f, 0.f, 0.f};
    float ac1[4] = {0.f, 0.f, 0.f, 0.f};
    union { unsigned u; float f; } w;
    #define ACC(acv, av, zv)                                   \
        w.u = (zv).x << 16;         acv[0] = fmaf(av, w.f, acv[0]); \
        w.u = (zv).x & 0xFFFF0000u; acv[1] = fmaf(av, w.f, acv[1]); \
        w.u = (zv).y << 16;         acv[2] = fmaf(av, w.f, acv[2]); \
        w.u = (zv).y & 0xFFFF0000u; acv[3] = fmaf(av, w.f, acv[3]);
    ACC(ac0, a00, z00) ACC(ac0, a01, z01) ACC(ac0, a02, z02) ACC(ac0, a03, z03)
    ACC(ac1, a10, z10) ACC(ac1, a11, z11) ACC(ac1, a12, z12) ACC(ac1, a13, z13)
    #undef ACC

    // reduce over g (lane bits 4,5)
    #pragma unroll
    for (int c = 0; c < 4; ++c) {
        ac0[c] += __shfl_xor(ac0[c], 16, 64);
        ac0[c] += __shfl_xor(ac0[c], 32, 64);
        ac1[c] += __shfl_xor(ac1[c], 16, 64);
        ac1[c] += __shfl_xor(ac1[c], 32, 64);
    }

    if (g == 0) {
        *reinterpret_cast<float4*>(out + (size_t)n0 * OUTDIM + c4 * 4) =
            make_float4(ac0[0], ac0[1], ac0[2], ac0[3]);
        if (n1 != n0)
            *reinterpret_cast<float4*>(out + (size_t)n1 * OUTDIM + c4 * 4) =
                make_float4(ac1[0], ac1[1], ac1[2], ac1[3]);
    }
}

extern "C" void kernel_launch(void* const* d_in, const int* in_sizes, int n_in,
                              void* d_out, int out_size, void* d_ws, size_t ws_size,
                              hipStream_t stream) {
    const float* h      = (const float*)d_in[0];
    const int*   nbr    = (const int*)  d_in[1];
    const float* wbias  = (const float*)d_in[2];
    const float* W_fc   = (const float*)d_in[3];
    const float* W_attn = (const float*)d_in[4];
    float* out = (float*)d_out;

    const int n = in_sizes[0] / INDIM;   // 100000

    // ws: zb (n*64 bf16) | s_src (n f32) | s_dst (n f32) | alpha (n*16 f32) | wfrag (4096 u32)
    __hip_bfloat16* zb = (__hip_bfloat16*)d_ws;
    float* s_src = (float*)((char*)d_ws + (size_t)n * OUTDIM * sizeof(__hip_bfloat16));
    float* s_dst = s_src + n;
    float* alpha = s_dst + n;
    unsigned* wfrag = (unsigned*)(alpha + (size_t)n * DNBR);

    wprep<<<1, 256, 0, stream>>>(W_fc, wfrag);
    fc_mfma<<<(n + 63) / 64, 256, 0, stream>>>(h, wfrag, W_attn, zb, s_src, s_dst, n);
    alpha_kernel<<<(n + 255) / 256, 256, 0, stream>>>(nbr, wbias, s_src, s_dst, alpha, n);
    out_kernel<<<(n + 7) / 8, 256, 0, stream>>>(nbr, alpha, zb, out, n);
}